// Round 7
// baseline (2790.690 us; speedup 1.0000x reference)
//
#include <hip/hip_runtime.h>

#define BATCH 512
#define TLEN 128
#define DIN 512
#define HID 256
#define NCLS 96
#define STEPS 26
#define GRUIN 608
#define G3 768

#define BM 64
#define BN 64
#define BK 16
#define LDS_STRIDE 68

typedef unsigned short ushort_t;
typedef __attribute__((ext_vector_type(8))) short short8v;
typedef __attribute__((ext_vector_type(4))) float f32x4;
typedef __attribute__((ext_vector_type(8))) unsigned short ushort8v;

__device__ __forceinline__ float fast_tanh(float x) {
    return 1.f - 2.f / (__expf(2.f * x) + 1.f);
}
__device__ __forceinline__ float fast_sigmoid(float x) {
    return 1.f / (1.f + __expf(-x));
}
__device__ __forceinline__ ushort_t f2bf_rne(float f) {
    unsigned int u = __float_as_uint(f);
    unsigned int r = (u + 0x7FFFu + ((u >> 16) & 1u)) >> 16;
    return (ushort_t)r;
}
__device__ __forceinline__ float bf2f(ushort_t h) {
    return __uint_as_float(((unsigned int)h) << 16);
}
__device__ __forceinline__ float bflo(unsigned int v) {
    return __uint_as_float(v << 16);
}
__device__ __forceinline__ float bfhi(unsigned int v) {
    return __uint_as_float(v & 0xffff0000u);
}

// ================= one-time prep: pack/transpose/convert weights =================
__global__ __launch_bounds__(256)
void prep_all(const float* __restrict__ W_h2h, const float* __restrict__ W_hh,
              const float* __restrict__ W_ih, const float* __restrict__ W_i2h,
              const float* __restrict__ b_ih, const float* __restrict__ W_gen,
              ushort_t* __restrict__ WcatT, ushort_t* __restrict__ B16cat,
              float* __restrict__ WembT, ushort_t* __restrict__ Wgen16) {
    int idx = blockIdx.x * 256 + threadIdx.x;
    if (idx < 262144) {
        int k = idx >> 10, n = idx & 1023;
        float v = (n < 256) ? W_h2h[n * 256 + k] : W_hh[(size_t)(n - 256) * 256 + k];
        WcatT[idx] = f2bf_rne(v);
    } else if (idx < 262144 + 524288) {
        int j = idx - 262144;
        int r = j >> 9, c = j & 511;
        float v = (r < 768) ? W_ih[(size_t)r * GRUIN + c] : W_i2h[(size_t)(r - 768) * 512 + c];
        B16cat[j] = f2bf_rne(v);
    } else if (idx < 262144 + 524288 + 73728) {
        int j = idx - (262144 + 524288);
        int ch = j / 768, jj = j - ch * 768;
        WembT[j] = W_ih[(size_t)jj * GRUIN + 512 + ch] + b_ih[jj];
    } else if (idx < 262144 + 524288 + 73728 + 24576) {
        int j = idx - (262144 + 524288 + 73728);
        Wgen16[j] = f2bf_rne(W_gen[j]);
    }
}

// ================= fused MFMA GEMM: C16[65536,1024] = bf16(A_fp32) @ B16^T =================
#define PAD_ROW 40
__global__ __launch_bounds__(256)
void hwhp_mfma(const float* __restrict__ A,
               const ushort_t* __restrict__ B16,
               ushort_t* __restrict__ C16) {
    __shared__ ushort_t As[128 * PAD_ROW];
    __shared__ ushort_t Bs[128 * PAD_ROW];
    const int wgid = blockIdx.x;
    const int mt = (wgid & 7) + ((wgid >> 6) << 3);
    const int nt = (wgid >> 3) & 7;
    const int bm = mt * 128, bn = nt * 128;
    const int tid = threadIdx.x;
    const int wid = tid >> 6, lane = tid & 63;
    const int wr = wid >> 1, wc = wid & 1;
    const int sr = tid >> 2, sq = tid & 3;
    f32x4 acc[4][4] = {};
    const int l15 = lane & 15, lhi = lane >> 4;
    for (int k0 = 0; k0 < 512; k0 += 32) {
        const float* a0p = A + (size_t)(bm + sr) * 512 + k0 + sq * 8;
        const float* a1p = A + (size_t)(bm + sr + 64) * 512 + k0 + sq * 8;
        float4 fa0 = *(const float4*)a0p;
        float4 fa1 = *(const float4*)(a0p + 4);
        float4 fc0 = *(const float4*)a1p;
        float4 fc1 = *(const float4*)(a1p + 4);
        ushort8v b0 = *(const ushort8v*)(B16 + (size_t)(bn + sr) * 512 + k0 + sq * 8);
        ushort8v b1 = *(const ushort8v*)(B16 + (size_t)(bn + sr + 64) * 512 + k0 + sq * 8);
        ushort8v ua, uc;
        ua[0] = f2bf_rne(fa0.x); ua[1] = f2bf_rne(fa0.y);
        ua[2] = f2bf_rne(fa0.z); ua[3] = f2bf_rne(fa0.w);
        ua[4] = f2bf_rne(fa1.x); ua[5] = f2bf_rne(fa1.y);
        ua[6] = f2bf_rne(fa1.z); ua[7] = f2bf_rne(fa1.w);
        uc[0] = f2bf_rne(fc0.x); uc[1] = f2bf_rne(fc0.y);
        uc[2] = f2bf_rne(fc0.z); uc[3] = f2bf_rne(fc0.w);
        uc[4] = f2bf_rne(fc1.x); uc[5] = f2bf_rne(fc1.y);
        uc[6] = f2bf_rne(fc1.z); uc[7] = f2bf_rne(fc1.w);
        __syncthreads();
        *(ushort8v*)(&As[sr * PAD_ROW + sq * 8]) = ua;
        *(ushort8v*)(&As[(sr + 64) * PAD_ROW + sq * 8]) = uc;
        *(ushort8v*)(&Bs[sr * PAD_ROW + sq * 8]) = b0;
        *(ushort8v*)(&Bs[(sr + 64) * PAD_ROW + sq * 8]) = b1;
        __syncthreads();
        short8v af[4], bfr[4];
#pragma unroll
        for (int i = 0; i < 4; ++i) {
            int arow = wr * 64 + i * 16 + l15;
            af[i] = *(const short8v*)(&As[arow * PAD_ROW + lhi * 8]);
            int brow = wc * 64 + i * 16 + l15;
            bfr[i] = *(const short8v*)(&Bs[brow * PAD_ROW + lhi * 8]);
        }
#pragma unroll
        for (int i = 0; i < 4; ++i)
#pragma unroll
            for (int j = 0; j < 4; ++j)
                acc[i][j] = __builtin_amdgcn_mfma_f32_16x16x32_bf16(af[i], bfr[j], acc[i][j], 0, 0, 0);
    }
    const int cr0 = bm + wr * 64 + lhi * 4;
    const int cc0 = bn + wc * 64 + l15;
#pragma unroll
    for (int i = 0; i < 4; ++i)
#pragma unroll
        for (int j = 0; j < 4; ++j)
#pragma unroll
            for (int p = 0; p < 4; ++p)
                C16[(size_t)(cr0 + i * 16 + p) * 1024 + cc0 + j * 16] = f2bf_rne(acc[i][j][p]);
}

// ================= persistent-register decoder v2: 1 row/block, 1024 threads =================
// Thread (th=tid>>9, cp=tid&511) holds 64 u32 = cols {2cp,2cp+1} for t in [th*64, th*64+64).
// 64 persistent VGPRs + working set fits the 128-VGPR hard cap of a 16-wave block.
__global__ __launch_bounds__(1024, 4)
void decoder_reg(const ushort_t* __restrict__ HWHp,   // [B*T][1024] bf16
                 const ushort_t* __restrict__ WcatT,  // [256][1024] bf16
                 const float* __restrict__ WembT,     // [96][768]
                 const ushort_t* __restrict__ Wgen16, // [96][256] bf16
                 const float* __restrict__ b_h2h,
                 const float* __restrict__ b_hh,
                 const float* __restrict__ Wscore,
                 const float* __restrict__ b_gen,
                 const int* __restrict__ text,
                 float* __restrict__ out) {
    const int b = blockIdx.x;
    const int tid = threadIdx.x;   // 1024
    const int wave = tid >> 6, lane = tid & 63;
    const int th = tid >> 9;       // t-half 0/1
    const int cp = tid & 511;      // u32 col-pair 0..511

    __shared__ __align__(16) ushort_t hp_lds[TLEN * HID];  // 64KB
    __shared__ __align__(16) float parts[2][1024];          // 8KB partial buffer
    __shared__ __align__(16) float hg[1024];
    __shared__ __align__(16) float gi_l[G3];
    __shared__ __align__(16) float hidden_l[HID];
    __shared__ __align__(16) float wsc[HID];
    __shared__ __align__(16) float bc[1024];
    __shared__ float bg[NCLS];
    __shared__ float es[TLEN];
    __shared__ float al[TLEN];
    __shared__ float red[16];

    const size_t rowbase = (size_t)b * TLEN;
    const unsigned int* Hu = (const unsigned int*)HWHp;   // 512 u32 per row

    // persistent register tile: 64 u32 per thread
    unsigned int r[64];
#pragma unroll
    for (int j = 0; j < 64; ++j) {
        r[j] = Hu[(rowbase + th * 64 + j) * 512 + cp];
        asm volatile("" : "+v"(r[j]));
    }

    // Hp (u32 col-pairs 384..511) -> LDS
    {
        unsigned int* hp_u = (unsigned int*)hp_lds;
#pragma unroll
        for (int k = 0; k < 16; ++k) {
            int j = k * 1024 + tid;          // 0..16383
            int t = j >> 7, c = j & 127;
            hp_u[t * 128 + c] = Hu[(rowbase + t) * 512 + 384 + c];
        }
    }
    if (tid < 256) { wsc[tid] = Wscore[tid]; hidden_l[tid] = 0.f; }
    bc[tid] = (tid < 256) ? b_h2h[tid] : b_hh[tid - 256];
    if (tid < NCLS) bg[tid] = b_gen[tid];
    __syncthreads();

    const unsigned int* Wu = (const unsigned int*)WcatT;  // [256][512] u32
    const int* textb = text + b * STEPS;

    for (int s = 0; s < STEPS; ++s) {
        // ---- phase 1a: partial GEMV over k-half  (thread -> cols 2cp,2cp+1)
        {
            float a0 = 0.f, a1 = 0.f;
            const unsigned int* wp = Wu + (size_t)th * 128 * 512 + cp;
            const float* hl = &hidden_l[th * 128];
#pragma unroll 8
            for (int k = 0; k < 128; ++k) {
                unsigned int w = wp[(size_t)k * 512];
                float h = hl[k];
                a0 = fmaf(h, bflo(w), a0);
                a1 = fmaf(h, bfhi(w), a1);
            }
            parts[th][2 * cp] = a0;
            parts[th][2 * cp + 1] = a1;
        }
        __syncthreads();
        // ---- phase 1b: combine halves + bias
        hg[tid] = parts[0][tid] + parts[1][tid] + bc[tid];
        __syncthreads();
        // ---- phase 2: e[t] = W_score . tanh(Hp[t] + h_proj)   (wave per t, 16 waves)
#pragma unroll
        for (int i = 0; i < 8; ++i) {
            int t = i * 16 + wave;
            ushort4 hv = *(const ushort4*)(hp_lds + t * 256 + lane * 4);
            float4 hpv = *(const float4*)(&hg[lane * 4]);
            float4 wv = *(const float4*)(&wsc[lane * 4]);
            float sc = fast_tanh(bf2f(hv.x) + hpv.x) * wv.x
                     + fast_tanh(bf2f(hv.y) + hpv.y) * wv.y
                     + fast_tanh(bf2f(hv.z) + hpv.z) * wv.z
                     + fast_tanh(bf2f(hv.w) + hpv.w) * wv.w;
#pragma unroll
            for (int off = 32; off >= 1; off >>= 1) sc += __shfl_xor(sc, off);
            if (lane == 0) es[t] = sc;
        }
        __syncthreads();
        // ---- phase 3: softmax over es[0..127] (threads 0..127 = waves 0,1)
        float ev = 0.f, p = 0.f;
        if (tid < TLEN) {
            ev = es[tid];
            float mx = ev;
#pragma unroll
            for (int off = 32; off >= 1; off >>= 1) mx = fmaxf(mx, __shfl_xor(mx, off));
            if (lane == 0) red[wave] = mx;
        }
        __syncthreads();
        if (tid < TLEN) {
            float m = fmaxf(red[0], red[1]);
            p = __expf(ev - m);
            float sm = p;
#pragma unroll
            for (int off = 32; off >= 1; off >>= 1) sm += __shfl_xor(sm, off);
            if (lane == 0) red[8 + wave] = sm;
        }
        __syncthreads();
        if (tid < TLEN) al[tid] = p / (red[8] + red[9]);
        __syncthreads();
        // ---- phase 4a: partial gi over t-half (pure register FMA, cp<384)
        if (cp < 384) {
            float g0 = 0.f, g1 = 0.f;
            const float* alh = &al[th * 64];
#pragma unroll
            for (int j = 0; j < 64; ++j) {
                float a = alh[j];
                g0 = fmaf(a, bflo(r[j]), g0);
                g1 = fmaf(a, bfhi(r[j]), g1);
            }
            parts[th][2 * cp] = g0;
            parts[th][2 * cp + 1] = g1;
        }
        __syncthreads();
        // ---- phase 4b: combine halves
        if (tid < G3) gi_l[tid] = parts[0][tid] + parts[1][tid];
        __syncthreads();
        // ---- phase 5: GRU gates (threads 0..255)
        if (tid < 256) {
            int ch = textb[s];
            const float* em = WembT + (size_t)ch * G3;
            float ir = gi_l[tid]       + em[tid]       + hg[256 + tid];
            float iz = gi_l[256 + tid] + em[256 + tid] + hg[512 + tid];
            float in_ = gi_l[512 + tid] + em[512 + tid];
            float hn = hg[768 + tid];
            float rr = fast_sigmoid(ir);
            float zz = fast_sigmoid(iz);
            float nn = fast_tanh(in_ + rr * hn);
            hidden_l[tid] = (1.f - zz) * nn + zz * hidden_l[tid];
        }
        __syncthreads();
        // ---- phase 6: generator (threads 0..95)
        if (tid < NCLS) {
            const ushort_t* wrow = Wgen16 + (size_t)tid * HID;
            float acc = bg[tid];
#pragma unroll 4
            for (int k = 0; k < HID; k += 8) {
                ushort8v w8 = *(const ushort8v*)(wrow + k);
                acc = fmaf(hidden_l[k],     bf2f(w8[0]), acc);
                acc = fmaf(hidden_l[k + 1], bf2f(w8[1]), acc);
                acc = fmaf(hidden_l[k + 2], bf2f(w8[2]), acc);
                acc = fmaf(hidden_l[k + 3], bf2f(w8[3]), acc);
                acc = fmaf(hidden_l[k + 4], bf2f(w8[4]), acc);
                acc = fmaf(hidden_l[k + 5], bf2f(w8[5]), acc);
                acc = fmaf(hidden_l[k + 6], bf2f(w8[6]), acc);
                acc = fmaf(hidden_l[k + 7], bf2f(w8[7]), acc);
            }
            out[((size_t)b * STEPS + s) * NCLS + tid] = acc;
        }
        __syncthreads();
    }
}

// ================= fallback (round-3 Plan B, validated) =================
template <typename OutT>
__device__ __forceinline__ void store_c(OutT* p, float v);
template <> __device__ __forceinline__ void store_c<float>(float* p, float v) { *p = v; }
template <> __device__ __forceinline__ void store_c<ushort_t>(ushort_t* p, float v) { *p = f2bf_rne(v); }

template <typename OutT>
__global__ __launch_bounds__(256)
void gemm_nt(const float* __restrict__ A, int lda,
             const float* __restrict__ Bw, int ldb,
             OutT* __restrict__ Cc, int ldc,
             const float* __restrict__ bias,
             int M, int N, int K) {
    __shared__ float As[BK][LDS_STRIDE];
    __shared__ float Bs[BK][LDS_STRIDE];
    const int tid = threadIdx.x;
    const int bm = blockIdx.x * BM;
    const int bn = blockIdx.y * BN;
    const int tx = tid & 15, ty = tid >> 4;
    const int lr = tid >> 2;
    const int lc = (tid & 3) << 2;
    float acc[4][4] = {};
    const int gr = bm + lr;
    const int gn = bn + lr;
    const float* Arow = A + (size_t)gr * lda;
    const float* Brow = Bw + (size_t)gn * ldb;
    for (int k0 = 0; k0 < K; k0 += BK) {
        float4 va = make_float4(0.f, 0.f, 0.f, 0.f);
        float4 vb = make_float4(0.f, 0.f, 0.f, 0.f);
        if (gr < M) va = *(const float4*)(Arow + k0 + lc);
        if (gn < N) vb = *(const float4*)(Brow + k0 + lc);
        As[lc + 0][lr] = va.x; As[lc + 1][lr] = va.y;
        As[lc + 2][lr] = va.z; As[lc + 3][lr] = va.w;
        Bs[lc + 0][lr] = vb.x; Bs[lc + 1][lr] = vb.y;
        Bs[lc + 2][lr] = vb.z; Bs[lc + 3][lr] = vb.w;
        __syncthreads();
#pragma unroll
        for (int k = 0; k < BK; ++k) {
            float4 a4 = *(const float4*)(&As[k][ty << 2]);
            float4 b4 = *(const float4*)(&Bs[k][tx << 2]);
            float a[4] = {a4.x, a4.y, a4.z, a4.w};
            float b[4] = {b4.x, b4.y, b4.z, b4.w};
#pragma unroll
            for (int i = 0; i < 4; ++i)
#pragma unroll
                for (int j = 0; j < 4; ++j)
                    acc[i][j] = fmaf(a[i], b[j], acc[i][j]);
        }
        __syncthreads();
    }
#pragma unroll
    for (int i = 0; i < 4; ++i) {
        int m = bm + (ty << 2) + i;
        if (m >= M) continue;
#pragma unroll
        for (int j = 0; j < 4; ++j) {
            int n = bn + (tx << 2) + j;
            if (n < N) store_c(&Cc[(size_t)m * ldc + n], acc[i][j] + (bias ? bias[n] : 0.f));
        }
    }
}

__global__ __launch_bounds__(256)
void prep_wcat(const float* __restrict__ W_h2h, const float* __restrict__ W_hh,
               const float* __restrict__ b_h2h, const float* __restrict__ b_hh,
               float* __restrict__ Wcat, float* __restrict__ bcat,
               float* __restrict__ hidden) {
    int idx = blockIdx.x * 256 + threadIdx.x;
    int r = idx >> 8, c = idx & 255;
    Wcat[idx] = (r < 256) ? W_h2h[r * 256 + c] : W_hh[(r - 256) * 256 + c];
    if (idx < 1024) bcat[idx] = (idx < 256) ? b_h2h[idx] : b_hh[idx - 256];
    if (idx < BATCH * HID) hidden[idx] = 0.f;
}

template <typename HT>
__global__ __launch_bounds__(256)
void attn_step(const HT* __restrict__ Hproj,
               const float* __restrict__ batchH,
               const float* __restrict__ hg,
               const float* __restrict__ Wscore,
               float* __restrict__ context) {
    const int b = blockIdx.x;
    const int tid = threadIdx.x;
    __shared__ float hp[HID];
    __shared__ float wsc[HID];
    __shared__ float es[TLEN];
    __shared__ float red[16];
    hp[tid] = hg[b * 1024 + tid];
    wsc[tid] = Wscore[tid];
    __syncthreads();
    const int wave = tid >> 6;
    const int lane = tid & 63;
    const HT* Hp = Hproj + (size_t)b * TLEN * HID;
    for (int t = wave; t < TLEN; t += 4) {
        float x0, x1, x2, x3;
        if constexpr (sizeof(HT) == 4) {
            float4 hv = *(const float4*)((const float*)Hp + (size_t)t * HID + (lane << 2));
            x0 = hv.x; x1 = hv.y; x2 = hv.z; x3 = hv.w;
        } else {
            ushort4 hv = *(const ushort4*)((const ushort_t*)Hp + (size_t)t * HID + (lane << 2));
            x0 = bf2f(hv.x); x1 = bf2f(hv.y); x2 = bf2f(hv.z); x3 = bf2f(hv.w);
        }
        float4 hpv = *(const float4*)(&hp[lane << 2]);
        float4 wv = *(const float4*)(&wsc[lane << 2]);
        float sc = fast_tanh(x0 + hpv.x) * wv.x
                 + fast_tanh(x1 + hpv.y) * wv.y
                 + fast_tanh(x2 + hpv.z) * wv.z
                 + fast_tanh(x3 + hpv.w) * wv.w;
#pragma unroll
        for (int off = 32; off >= 1; off >>= 1) sc += __shfl_xor(sc, off);
        if (lane == 0) es[t] = sc;
    }
    __syncthreads();
    float e = (tid < TLEN) ? es[tid] : -INFINITY;
    float m = e;
#pragma unroll
    for (int off = 32; off >= 1; off >>= 1) m = fmaxf(m, __shfl_xor(m, off));
    if (lane == 0) red[wave] = m;
    __syncthreads();
    m = fmaxf(fmaxf(red[0], red[1]), fmaxf(red[2], red[3]));
    float p = (tid < TLEN) ? __expf(e - m) : 0.f;
    float ss = p;
#pragma unroll
    for (int off = 32; off >= 1; off >>= 1) ss += __shfl_xor(ss, off);
    if (lane == 0) red[8 + wave] = ss;
    __syncthreads();
    float denom = red[8] + red[9] + red[10] + red[11];
    if (tid < TLEN) es[tid] = p / denom;
    __syncthreads();
    const float* Hb = batchH + (size_t)b * TLEN * DIN;
    float acc0 = 0.f, acc1 = 0.f;
#pragma unroll 4
    for (int t = 0; t < TLEN; ++t) {
        float a = es[t];
        acc0 = fmaf(a, Hb[(size_t)t * DIN + tid], acc0);
        acc1 = fmaf(a, Hb[(size_t)t * DIN + HID + tid], acc1);
    }
    context[(size_t)b * DIN + tid] = acc0;
    context[(size_t)b * DIN + HID + tid] = acc1;
}

__global__ __launch_bounds__(256)
void gru_gate_gen(const float* __restrict__ gi,
                  const float* __restrict__ hg,
                  float* __restrict__ hidden,
                  float* __restrict__ out,
                  const int* __restrict__ text,
                  int s,
                  const float* __restrict__ W_ih,
                  const float* __restrict__ W_gen,
                  const float* __restrict__ b_gen) {
    const int b = blockIdx.x;
    const int h = threadIdx.x;
    __shared__ float sh[HID];
    const int ch = text[b * STEPS + s];
    const float* gib = gi + (size_t)b * G3;
    const float* ghb = hg + (size_t)b * 1024 + 256;
    float ir = gib[h]        + W_ih[(size_t)h * GRUIN + DIN + ch];
    float iz = gib[256 + h]  + W_ih[(size_t)(256 + h) * GRUIN + DIN + ch];
    float in_ = gib[512 + h] + W_ih[(size_t)(512 + h) * GRUIN + DIN + ch];
    float hr = ghb[h];
    float hz = ghb[256 + h];
    float hn = ghb[512 + h];
    float r = fast_sigmoid(ir + hr);
    float z = fast_sigmoid(iz + hz);
    float n = fast_tanh(in_ + r * hn);
    float hprev = hidden[b * HID + h];
    float nh = (1.f - z) * n + z * hprev;
    hidden[b * HID + h] = nh;
    sh[h] = nh;
    __syncthreads();
    if (h < NCLS) {
        const float* wg = W_gen + (size_t)h * HID;
        float acc = b_gen[h];
#pragma unroll 4
        for (int k = 0; k < HID; k += 4) {
            float4 w4 = *(const float4*)(wg + k);
            acc = fmaf(sh[k], w4.x, acc);
            acc = fmaf(sh[k + 1], w4.y, acc);
            acc = fmaf(sh[k + 2], w4.z, acc);
            acc = fmaf(sh[k + 3], w4.w, acc);
        }
        out[((size_t)b * STEPS + s) * NCLS + h] = acc;
    }
}

extern "C" void kernel_launch(void* const* d_in, const int* in_sizes, int n_in,
                              void* d_out, int out_size, void* d_ws, size_t ws_size,
                              hipStream_t stream) {
    const float* batch_H = (const float*)d_in[0];
    const int* text      = (const int*)d_in[1];
    const float* W_i2h   = (const float*)d_in[3];
    const float* W_h2h   = (const float*)d_in[4];
    const float* b_h2h   = (const float*)d_in[5];
    const float* W_score = (const float*)d_in[6];
    const float* W_ih    = (const float*)d_in[7];
    const float* W_hh    = (const float*)d_in[8];
    const float* b_ih    = (const float*)d_in[9];
    const float* b_hh    = (const float*)d_in[10];
    const float* W_gen   = (const float*)d_in[11];
    const float* b_gen   = (const float*)d_in[12];
    float* out = (float*)d_out;
    char* ws = (char*)d_ws;

    const size_t M = (size_t)BATCH * TLEN;              // 65536
    const size_t hwhp_bytes  = M * 1024 * 2;            // 134,217,728
    const size_t b16cat_off  = hwhp_bytes;
    const size_t wcatT_off   = b16cat_off + 1048576;
    const size_t wgen16_off  = wcatT_off + 524288;
    const size_t wembT_off   = wgen16_off + 49152;
    const size_t need_new    = wembT_off + 294912;      // 136,134,656

    if (ws_size >= need_new) {
        ushort_t* HWHp   = (ushort_t*)ws;
        ushort_t* B16cat = (ushort_t*)(ws + b16cat_off);
        ushort_t* WcatT  = (ushort_t*)(ws + wcatT_off);
        ushort_t* Wgen16 = (ushort_t*)(ws + wgen16_off);
        float*    WembT  = (float*)(ws + wembT_off);

        hipLaunchKernelGGL(prep_all, dim3(3456), dim3(256), 0, stream,
                           W_h2h, W_hh, W_ih, W_i2h, b_ih, W_gen,
                           WcatT, B16cat, WembT, Wgen16);
        hipLaunchKernelGGL(hwhp_mfma, dim3((M / 128) * 8), dim3(256), 0, stream,
                           batch_H, B16cat, HWHp);
        hipLaunchKernelGGL(decoder_reg, dim3(BATCH), dim3(1024), 0, stream,
                           HWHp, WcatT, WembT, Wgen16, b_h2h, b_hh, W_score, b_gen,
                           text, out);
        return;
    }

    // ---------------- fallback: round-3 Plan B ----------------
    const size_t nHp = M * HID;
    const size_t small_floats = (size_t)BATCH * HID + BATCH * 1024 + BATCH * DIN
                              + BATCH * G3 + 1024 * HID + 1024;
    const size_t need_B32 = nHp * 4 + small_floats * 4;
    const bool use_fp32 = (ws_size >= need_B32);
    const size_t hp_bytes = use_fp32 ? nHp * 4 : nHp * 2;
    void* Hproj = (void*)ws;
    float* hidden  = (float*)(ws + hp_bytes);
    float* hg      = hidden + BATCH * HID;
    float* context = hg + BATCH * 1024;
    float* gi      = context + BATCH * DIN;
    float* Wcat    = gi + BATCH * G3;
    float* bcat    = Wcat + 1024 * HID;

    hipLaunchKernelGGL(prep_wcat, dim3(1024), dim3(256), 0, stream,
                       W_h2h, W_hh, b_h2h, b_hh, Wcat, bcat, hidden);
    if (use_fp32) {
        hipLaunchKernelGGL(gemm_nt<float>, dim3(M / BM, HID / BN), dim3(256), 0, stream,
                           batch_H, DIN, W_i2h, DIN, (float*)Hproj, HID, (const float*)nullptr,
                           (int)M, HID, DIN);
    } else {
        hipLaunchKernelGGL(gemm_nt<ushort_t>, dim3(M / BM, HID / BN), dim3(256), 0, stream,
                           batch_H, DIN, W_i2h, DIN, (ushort_t*)Hproj, HID, (const float*)nullptr,
                           (int)M, HID, DIN);
    }
    for (int s = 0; s < STEPS; ++s) {
        hipLaunchKernelGGL(gemm_nt<float>, dim3(BATCH / BM, 1024 / BN), dim3(256), 0, stream,
                           hidden, HID, Wcat, HID, hg, 1024, bcat, BATCH, 1024, HID);
        if (use_fp32) {
            hipLaunchKernelGGL(attn_step<float>, dim3(BATCH), dim3(256), 0, stream,
                               (const float*)Hproj, batch_H, hg, W_score, context);
        } else {
            hipLaunchKernelGGL(attn_step<ushort_t>, dim3(BATCH), dim3(256), 0, stream,
                               (const ushort_t*)Hproj, batch_H, hg, W_score, context);
        }
        hipLaunchKernelGGL(gemm_nt<float>, dim3(BATCH / BM, G3 / BN), dim3(256), 0, stream,
                           context, DIN, W_ih, GRUIN, gi, G3, b_ih, BATCH, G3, DIN);
        hipLaunchKernelGGL(gru_gate_gen, dim3(BATCH), dim3(HID), 0, stream,
                           gi, hg, hidden, out, text, s, W_ih, W_gen, b_gen);
    }
}

// Round 8
// 1450.340 us; speedup vs baseline: 1.9242x; 1.9242x over previous
//
#include <hip/hip_runtime.h>

#define BATCH 512
#define TLEN 128
#define DIN 512
#define HID 256
#define NCLS 96
#define STEPS 26
#define GRUIN 608
#define G3 768

#define BM 64
#define BN 64
#define BK 16
#define LDS_STRIDE 68

typedef unsigned short ushort_t;
typedef __attribute__((ext_vector_type(8))) short short8v;
typedef __attribute__((ext_vector_type(4))) float f32x4;
typedef __attribute__((ext_vector_type(8))) unsigned short ushort8v;

__device__ __forceinline__ float fast_tanh(float x) {
    return 1.f - 2.f / (__expf(2.f * x) + 1.f);
}
__device__ __forceinline__ float fast_sigmoid(float x) {
    return 1.f / (1.f + __expf(-x));
}
__device__ __forceinline__ ushort_t f2bf_rne(float f) {
    unsigned int u = __float_as_uint(f);
    unsigned int r = (u + 0x7FFFu + ((u >> 16) & 1u)) >> 16;
    return (ushort_t)r;
}
__device__ __forceinline__ float bf2f(ushort_t h) {
    return __uint_as_float(((unsigned int)h) << 16);
}
__device__ __forceinline__ float bflo(unsigned int v) {
    return __uint_as_float(v << 16);
}
__device__ __forceinline__ float bfhi(unsigned int v) {
    return __uint_as_float(v & 0xffff0000u);
}

// ================= one-time prep =================
// WcatF fp32 [1024][256] rows=outputs (h_proj|gh), bcat fp32 [1024]
// B16cat bf16 [1024][512] rows 0..767 = W_ih[:, :512]; 768..1023 = W_i2h
// WembT fp32 [96][768]: W_ih[j][512+ch] + b_ih[j]
// Wgen16 bf16 [96][256]; hidden zeroed
__global__ __launch_bounds__(256)
void prep_all(const float* __restrict__ W_h2h, const float* __restrict__ W_hh,
              const float* __restrict__ W_ih, const float* __restrict__ W_i2h,
              const float* __restrict__ b_ih, const float* __restrict__ b_h2h,
              const float* __restrict__ b_hh, const float* __restrict__ W_gen,
              float* __restrict__ WcatF, ushort_t* __restrict__ B16cat,
              float* __restrict__ WembT, ushort_t* __restrict__ Wgen16,
              float* __restrict__ bcat, float* __restrict__ hidden) {
    int idx = blockIdx.x * 256 + threadIdx.x;
    if (idx < 262144) {
        int r = idx >> 8, c = idx & 255;
        WcatF[idx] = (r < 256) ? W_h2h[r * 256 + c] : W_hh[(size_t)(r - 256) * 256 + c];
    } else if (idx < 262144 + 524288) {
        int j = idx - 262144;
        int r = j >> 9, c = j & 511;
        float v = (r < 768) ? W_ih[(size_t)r * GRUIN + c] : W_i2h[(size_t)(r - 768) * 512 + c];
        B16cat[j] = f2bf_rne(v);
    } else if (idx < 262144 + 524288 + 73728) {
        int j = idx - (262144 + 524288);
        int ch = j / 768, jj = j - ch * 768;
        WembT[j] = W_ih[(size_t)jj * GRUIN + 512 + ch] + b_ih[jj];
    } else if (idx < 262144 + 524288 + 73728 + 24576) {
        int j = idx - (262144 + 524288 + 73728);
        Wgen16[j] = f2bf_rne(W_gen[j]);
    } else if (idx < 262144 + 524288 + 73728 + 24576 + 1024) {
        int j = idx - (262144 + 524288 + 73728 + 24576);
        bcat[j] = (j < 256) ? b_h2h[j] : b_hh[j - 256];
    } else if (idx < 262144 + 524288 + 73728 + 24576 + 1024 + 131072) {
        int j = idx - (262144 + 524288 + 73728 + 24576 + 1024);
        hidden[j] = 0.f;
    }
}

// ================= fused MFMA GEMM: C16[65536,1024] = bf16(A_fp32) @ B16^T =================
#define PAD_ROW 40
__global__ __launch_bounds__(256)
void hwhp_mfma(const float* __restrict__ A,
               const ushort_t* __restrict__ B16,
               ushort_t* __restrict__ C16) {
    __shared__ ushort_t As[128 * PAD_ROW];
    __shared__ ushort_t Bs[128 * PAD_ROW];
    const int wgid = blockIdx.x;
    const int mt = (wgid & 7) + ((wgid >> 6) << 3);
    const int nt = (wgid >> 3) & 7;
    const int bm = mt * 128, bn = nt * 128;
    const int tid = threadIdx.x;
    const int wid = tid >> 6, lane = tid & 63;
    const int wr = wid >> 1, wc = wid & 1;
    const int sr = tid >> 2, sq = tid & 3;
    f32x4 acc[4][4] = {};
    const int l15 = lane & 15, lhi = lane >> 4;
    for (int k0 = 0; k0 < 512; k0 += 32) {
        const float* a0p = A + (size_t)(bm + sr) * 512 + k0 + sq * 8;
        const float* a1p = A + (size_t)(bm + sr + 64) * 512 + k0 + sq * 8;
        float4 fa0 = *(const float4*)a0p;
        float4 fa1 = *(const float4*)(a0p + 4);
        float4 fc0 = *(const float4*)a1p;
        float4 fc1 = *(const float4*)(a1p + 4);
        ushort8v b0 = *(const ushort8v*)(B16 + (size_t)(bn + sr) * 512 + k0 + sq * 8);
        ushort8v b1 = *(const ushort8v*)(B16 + (size_t)(bn + sr + 64) * 512 + k0 + sq * 8);
        ushort8v ua, uc;
        ua[0] = f2bf_rne(fa0.x); ua[1] = f2bf_rne(fa0.y);
        ua[2] = f2bf_rne(fa0.z); ua[3] = f2bf_rne(fa0.w);
        ua[4] = f2bf_rne(fa1.x); ua[5] = f2bf_rne(fa1.y);
        ua[6] = f2bf_rne(fa1.z); ua[7] = f2bf_rne(fa1.w);
        uc[0] = f2bf_rne(fc0.x); uc[1] = f2bf_rne(fc0.y);
        uc[2] = f2bf_rne(fc0.z); uc[3] = f2bf_rne(fc0.w);
        uc[4] = f2bf_rne(fc1.x); uc[5] = f2bf_rne(fc1.y);
        uc[6] = f2bf_rne(fc1.z); uc[7] = f2bf_rne(fc1.w);
        __syncthreads();
        *(ushort8v*)(&As[sr * PAD_ROW + sq * 8]) = ua;
        *(ushort8v*)(&As[(sr + 64) * PAD_ROW + sq * 8]) = uc;
        *(ushort8v*)(&Bs[sr * PAD_ROW + sq * 8]) = b0;
        *(ushort8v*)(&Bs[(sr + 64) * PAD_ROW + sq * 8]) = b1;
        __syncthreads();
        short8v af[4], bfr[4];
#pragma unroll
        for (int i = 0; i < 4; ++i) {
            int arow = wr * 64 + i * 16 + l15;
            af[i] = *(const short8v*)(&As[arow * PAD_ROW + lhi * 8]);
            int brow = wc * 64 + i * 16 + l15;
            bfr[i] = *(const short8v*)(&Bs[brow * PAD_ROW + lhi * 8]);
        }
#pragma unroll
        for (int i = 0; i < 4; ++i)
#pragma unroll
            for (int j = 0; j < 4; ++j)
                acc[i][j] = __builtin_amdgcn_mfma_f32_16x16x32_bf16(af[i], bfr[j], acc[i][j], 0, 0, 0);
    }
    const int cr0 = bm + wr * 64 + lhi * 4;
    const int cc0 = bn + wc * 64 + l15;
#pragma unroll
    for (int i = 0; i < 4; ++i)
#pragma unroll
        for (int j = 0; j < 4; ++j)
#pragma unroll
            for (int p = 0; p < 4; ++p)
                C16[(size_t)(cr0 + i * 16 + p) * 1024 + cc0 + j * 16] = f2bf_rne(acc[i][j][p]);
}

// ================= per-step fused attention+GRU+generator (1 row/block) =================
__global__ __launch_bounds__(512)
void step_fused(const ushort_t* __restrict__ HWHp,   // [B*T][1024] bf16
                const float* __restrict__ hg,        // [B][1024] fp32 (h_proj | gh)
                const float* __restrict__ WembT,     // [96][768]
                const ushort_t* __restrict__ Wgen16, // [96][256]
                const float* __restrict__ Wscore,    // [256]
                const float* __restrict__ b_gen,
                const int* __restrict__ text,
                int s,
                float* __restrict__ hidden,          // [B][256] fp32 in/out
                float* __restrict__ out) {           // [B][STEPS][96]
    const int b = blockIdx.x;
    const int tid = threadIdx.x;   // 512
    const int wave = tid >> 6, lane = tid & 63;

    __shared__ __align__(16) float hp[HID];
    __shared__ __align__(16) float wsc[HID];
    __shared__ __align__(16) float parts[4][G3];   // 12 KB
    __shared__ __align__(16) float gi_l[G3];
    __shared__ __align__(16) float sh[HID];
    __shared__ float es[TLEN];
    __shared__ float al[TLEN];
    __shared__ float red[16];

    const size_t rowbase = (size_t)b * TLEN;
    if (tid < 256) {
        hp[tid] = hg[(size_t)b * 1024 + tid];
        wsc[tid] = Wscore[tid];
    }
    __syncthreads();

    // ---- pass 1: e[t] = W_score . tanh(Hp[t] + h_proj); wave per t (8B loads)
#pragma unroll 2
    for (int i = 0; i < 16; ++i) {
        int t = i * 8 + wave;
        ushort4 hv = *(const ushort4*)(HWHp + (rowbase + t) * 1024 + G3 + lane * 4);
        float4 hpv = *(const float4*)(&hp[lane * 4]);
        float4 wv = *(const float4*)(&wsc[lane * 4]);
        float sc = fast_tanh(bf2f(hv.x) + hpv.x) * wv.x
                 + fast_tanh(bf2f(hv.y) + hpv.y) * wv.y
                 + fast_tanh(bf2f(hv.z) + hpv.z) * wv.z
                 + fast_tanh(bf2f(hv.w) + hpv.w) * wv.w;
#pragma unroll
        for (int off = 32; off >= 1; off >>= 1) sc += __shfl_xor(sc, off);
        if (lane == 0) es[t] = sc;
    }
    __syncthreads();
    // ---- pass 2: softmax over es[0..127] (threads 0..127)
    float ev = 0.f, p = 0.f;
    if (tid < TLEN) {
        ev = es[tid];
        float mx = ev;
#pragma unroll
        for (int off = 32; off >= 1; off >>= 1) mx = fmaxf(mx, __shfl_xor(mx, off));
        if (lane == 0) red[wave] = mx;
    }
    __syncthreads();
    if (tid < TLEN) {
        float m = fmaxf(red[0], red[1]);
        p = __expf(ev - m);
        float sm = p;
#pragma unroll
        for (int off = 32; off >= 1; off >>= 1) sm += __shfl_xor(sm, off);
        if (lane == 0) red[8 + wave] = sm;
    }
    __syncthreads();
    if (tid < TLEN) al[tid] = p / (red[8] + red[9]);
    __syncthreads();
    // ---- pass 3: gi = sum_t al[t]*HW[t,:]; 4 t-groups x 96 quads, dwordx4 stream
    {
        const int tg = tid >> 7;        // 0..3
        const int cq = tid & 127;       // quad id; active < 96
        if (cq < 96) {
            float a0 = 0.f, a1 = 0.f, a2 = 0.f, a3 = 0.f;
            float a4 = 0.f, a5 = 0.f, a6 = 0.f, a7 = 0.f;
            const ushort_t* base = HWHp + (rowbase + tg * 32) * 1024 + cq * 8;
            const float* alh = &al[tg * 32];
#pragma unroll 4
            for (int i = 0; i < 32; ++i) {
                ushort8v v = *(const ushort8v*)(base + (size_t)i * 1024);
                float a = alh[i];
                a0 = fmaf(a, bf2f(v[0]), a0);
                a1 = fmaf(a, bf2f(v[1]), a1);
                a2 = fmaf(a, bf2f(v[2]), a2);
                a3 = fmaf(a, bf2f(v[3]), a3);
                a4 = fmaf(a, bf2f(v[4]), a4);
                a5 = fmaf(a, bf2f(v[5]), a5);
                a6 = fmaf(a, bf2f(v[6]), a6);
                a7 = fmaf(a, bf2f(v[7]), a7);
            }
            float* pr = &parts[tg][cq * 8];
            pr[0] = a0; pr[1] = a1; pr[2] = a2; pr[3] = a3;
            pr[4] = a4; pr[5] = a5; pr[6] = a6; pr[7] = a7;
        }
    }
    __syncthreads();
    if (tid < 384) {
        int c0 = 2 * tid, c1 = 2 * tid + 1;
        gi_l[c0] = parts[0][c0] + parts[1][c0] + parts[2][c0] + parts[3][c0];
        gi_l[c1] = parts[0][c1] + parts[1][c1] + parts[2][c1] + parts[3][c1];
    }
    __syncthreads();
    // ---- pass 4: GRU gates (threads 0..255)
    if (tid < 256) {
        const int ch = text[b * STEPS + s];
        const float* em = WembT + (size_t)ch * G3;
        const float* ghb = hg + (size_t)b * 1024 + 256;
        float ir = gi_l[tid]       + em[tid]       + ghb[tid];
        float iz = gi_l[256 + tid] + em[256 + tid] + ghb[256 + tid];
        float in_ = gi_l[512 + tid] + em[512 + tid];
        float hn = ghb[512 + tid];
        float rr = fast_sigmoid(ir);
        float zz = fast_sigmoid(iz);
        float nn = fast_tanh(in_ + rr * hn);
        float nh = (1.f - zz) * nn + zz * hidden[(size_t)b * HID + tid];
        hidden[(size_t)b * HID + tid] = nh;
        sh[tid] = nh;
    }
    __syncthreads();
    // ---- pass 5: generator (threads 0..95)
    if (tid < NCLS) {
        const ushort_t* wrow = Wgen16 + (size_t)tid * HID;
        float acc = b_gen[tid];
#pragma unroll 4
        for (int k = 0; k < HID; k += 8) {
            ushort8v w8 = *(const ushort8v*)(wrow + k);
            acc = fmaf(sh[k],     bf2f(w8[0]), acc);
            acc = fmaf(sh[k + 1], bf2f(w8[1]), acc);
            acc = fmaf(sh[k + 2], bf2f(w8[2]), acc);
            acc = fmaf(sh[k + 3], bf2f(w8[3]), acc);
            acc = fmaf(sh[k + 4], bf2f(w8[4]), acc);
            acc = fmaf(sh[k + 5], bf2f(w8[5]), acc);
            acc = fmaf(sh[k + 6], bf2f(w8[6]), acc);
            acc = fmaf(sh[k + 7], bf2f(w8[7]), acc);
        }
        out[((size_t)b * STEPS + s) * NCLS + tid] = acc;
    }
}

// ================= generic fp32 GEMM (also fallback) =================
template <typename OutT>
__device__ __forceinline__ void store_c(OutT* p, float v);
template <> __device__ __forceinline__ void store_c<float>(float* p, float v) { *p = v; }
template <> __device__ __forceinline__ void store_c<ushort_t>(ushort_t* p, float v) { *p = f2bf_rne(v); }

template <typename OutT>
__global__ __launch_bounds__(256)
void gemm_nt(const float* __restrict__ A, int lda,
             const float* __restrict__ Bw, int ldb,
             OutT* __restrict__ Cc, int ldc,
             const float* __restrict__ bias,
             int M, int N, int K) {
    __shared__ float As[BK][LDS_STRIDE];
    __shared__ float Bs[BK][LDS_STRIDE];
    const int tid = threadIdx.x;
    const int bm = blockIdx.x * BM;
    const int bn = blockIdx.y * BN;
    const int tx = tid & 15, ty = tid >> 4;
    const int lr = tid >> 2;
    const int lc = (tid & 3) << 2;
    float acc[4][4] = {};
    const int gr = bm + lr;
    const int gn = bn + lr;
    const float* Arow = A + (size_t)gr * lda;
    const float* Brow = Bw + (size_t)gn * ldb;
    for (int k0 = 0; k0 < K; k0 += BK) {
        float4 va = make_float4(0.f, 0.f, 0.f, 0.f);
        float4 vb = make_float4(0.f, 0.f, 0.f, 0.f);
        if (gr < M) va = *(const float4*)(Arow + k0 + lc);
        if (gn < N) vb = *(const float4*)(Brow + k0 + lc);
        As[lc + 0][lr] = va.x; As[lc + 1][lr] = va.y;
        As[lc + 2][lr] = va.z; As[lc + 3][lr] = va.w;
        Bs[lc + 0][lr] = vb.x; Bs[lc + 1][lr] = vb.y;
        Bs[lc + 2][lr] = vb.z; Bs[lc + 3][lr] = vb.w;
        __syncthreads();
#pragma unroll
        for (int k = 0; k < BK; ++k) {
            float4 a4 = *(const float4*)(&As[k][ty << 2]);
            float4 b4 = *(const float4*)(&Bs[k][tx << 2]);
            float a[4] = {a4.x, a4.y, a4.z, a4.w};
            float b[4] = {b4.x, b4.y, b4.z, b4.w};
#pragma unroll
            for (int i = 0; i < 4; ++i)
#pragma unroll
                for (int j = 0; j < 4; ++j)
                    acc[i][j] = fmaf(a[i], b[j], acc[i][j]);
        }
        __syncthreads();
    }
#pragma unroll
    for (int i = 0; i < 4; ++i) {
        int m = bm + (ty << 2) + i;
        if (m >= M) continue;
#pragma unroll
        for (int j = 0; j < 4; ++j) {
            int n = bn + (tx << 2) + j;
            if (n < N) store_c(&Cc[(size_t)m * ldc + n], acc[i][j] + (bias ? bias[n] : 0.f));
        }
    }
}

// ================= fallback kernels (round-3 Plan B, validated) =================
__global__ __launch_bounds__(256)
void prep_wcat(const float* __restrict__ W_h2h, const float* __restrict__ W_hh,
               const float* __restrict__ b_h2h, const float* __restrict__ b_hh,
               float* __restrict__ Wcat, float* __restrict__ bcat,
               float* __restrict__ hidden) {
    int idx = blockIdx.x * 256 + threadIdx.x;
    int r = idx >> 8, c = idx & 255;
    Wcat[idx] = (r < 256) ? W_h2h[r * 256 + c] : W_hh[(r - 256) * 256 + c];
    if (idx < 1024) bcat[idx] = (idx < 256) ? b_h2h[idx] : b_hh[idx - 256];
    if (idx < BATCH * HID) hidden[idx] = 0.f;
}

template <typename HT>
__global__ __launch_bounds__(256)
void attn_step(const HT* __restrict__ Hproj,
               const float* __restrict__ batchH,
               const float* __restrict__ hg,
               const float* __restrict__ Wscore,
               float* __restrict__ context) {
    const int b = blockIdx.x;
    const int tid = threadIdx.x;
    __shared__ float hp[HID];
    __shared__ float wsc[HID];
    __shared__ float es[TLEN];
    __shared__ float red[16];
    hp[tid] = hg[b * 1024 + tid];
    wsc[tid] = Wscore[tid];
    __syncthreads();
    const int wave = tid >> 6;
    const int lane = tid & 63;
    const HT* Hp = Hproj + (size_t)b * TLEN * HID;
    for (int t = wave; t < TLEN; t += 4) {
        float x0, x1, x2, x3;
        if constexpr (sizeof(HT) == 4) {
            float4 hv = *(const float4*)((const float*)Hp + (size_t)t * HID + (lane << 2));
            x0 = hv.x; x1 = hv.y; x2 = hv.z; x3 = hv.w;
        } else {
            ushort4 hv = *(const ushort4*)((const ushort_t*)Hp + (size_t)t * HID + (lane << 2));
            x0 = bf2f(hv.x); x1 = bf2f(hv.y); x2 = bf2f(hv.z); x3 = bf2f(hv.w);
        }
        float4 hpv = *(const float4*)(&hp[lane << 2]);
        float4 wv = *(const float4*)(&wsc[lane << 2]);
        float sc = fast_tanh(x0 + hpv.x) * wv.x
                 + fast_tanh(x1 + hpv.y) * wv.y
                 + fast_tanh(x2 + hpv.z) * wv.z
                 + fast_tanh(x3 + hpv.w) * wv.w;
#pragma unroll
        for (int off = 32; off >= 1; off >>= 1) sc += __shfl_xor(sc, off);
        if (lane == 0) es[t] = sc;
    }
    __syncthreads();
    float e = (tid < TLEN) ? es[tid] : -INFINITY;
    float m = e;
#pragma unroll
    for (int off = 32; off >= 1; off >>= 1) m = fmaxf(m, __shfl_xor(m, off));
    if (lane == 0) red[wave] = m;
    __syncthreads();
    m = fmaxf(fmaxf(red[0], red[1]), fmaxf(red[2], red[3]));
    float p = (tid < TLEN) ? __expf(e - m) : 0.f;
    float ss = p;
#pragma unroll
    for (int off = 32; off >= 1; off >>= 1) ss += __shfl_xor(ss, off);
    if (lane == 0) red[8 + wave] = ss;
    __syncthreads();
    float denom = red[8] + red[9] + red[10] + red[11];
    if (tid < TLEN) es[tid] = p / denom;
    __syncthreads();
    const float* Hb = batchH + (size_t)b * TLEN * DIN;
    float acc0 = 0.f, acc1 = 0.f;
#pragma unroll 4
    for (int t = 0; t < TLEN; ++t) {
        float a = es[t];
        acc0 = fmaf(a, Hb[(size_t)t * DIN + tid], acc0);
        acc1 = fmaf(a, Hb[(size_t)t * DIN + HID + tid], acc1);
    }
    context[(size_t)b * DIN + tid] = acc0;
    context[(size_t)b * DIN + HID + tid] = acc1;
}

__global__ __launch_bounds__(256)
void gru_gate_gen(const float* __restrict__ gi,
                  const float* __restrict__ hg,
                  float* __restrict__ hidden,
                  float* __restrict__ out,
                  const int* __restrict__ text,
                  int s,
                  const float* __restrict__ W_ih,
                  const float* __restrict__ W_gen,
                  const float* __restrict__ b_gen) {
    const int b = blockIdx.x;
    const int h = threadIdx.x;
    __shared__ float sh[HID];
    const int ch = text[b * STEPS + s];
    const float* gib = gi + (size_t)b * G3;
    const float* ghb = hg + (size_t)b * 1024 + 256;
    float ir = gib[h]        + W_ih[(size_t)h * GRUIN + DIN + ch];
    float iz = gib[256 + h]  + W_ih[(size_t)(256 + h) * GRUIN + DIN + ch];
    float in_ = gib[512 + h] + W_ih[(size_t)(512 + h) * GRUIN + DIN + ch];
    float hr = ghb[h];
    float hz = ghb[256 + h];
    float hn = ghb[512 + h];
    float r = fast_sigmoid(ir + hr);
    float z = fast_sigmoid(iz + hz);
    float n = fast_tanh(in_ + r * hn);
    float hprev = hidden[b * HID + h];
    float nh = (1.f - z) * n + z * hprev;
    hidden[b * HID + h] = nh;
    sh[h] = nh;
    __syncthreads();
    if (h < NCLS) {
        const float* wg = W_gen + (size_t)h * HID;
        float acc = b_gen[h];
#pragma unroll 4
        for (int k = 0; k < HID; k += 4) {
            float4 w4 = *(const float4*)(wg + k);
            acc = fmaf(sh[k], w4.x, acc);
            acc = fmaf(sh[k + 1], w4.y, acc);
            acc = fmaf(sh[k + 2], w4.z, acc);
            acc = fmaf(sh[k + 3], w4.w, acc);
        }
        out[((size_t)b * STEPS + s) * NCLS + h] = acc;
    }
}

extern "C" void kernel_launch(void* const* d_in, const int* in_sizes, int n_in,
                              void* d_out, int out_size, void* d_ws, size_t ws_size,
                              hipStream_t stream) {
    const float* batch_H = (const float*)d_in[0];
    const int* text      = (const int*)d_in[1];
    const float* W_i2h   = (const float*)d_in[3];
    const float* W_h2h   = (const float*)d_in[4];
    const float* b_h2h   = (const float*)d_in[5];
    const float* W_score = (const float*)d_in[6];
    const float* W_ih    = (const float*)d_in[7];
    const float* W_hh    = (const float*)d_in[8];
    const float* b_ih    = (const float*)d_in[9];
    const float* b_hh    = (const float*)d_in[10];
    const float* W_gen   = (const float*)d_in[11];
    const float* b_gen   = (const float*)d_in[12];
    float* out = (float*)d_out;
    char* ws = (char*)d_ws;

    const size_t M = (size_t)BATCH * TLEN;              // 65536
    // workspace layout (bytes)
    const size_t hwhp_off   = 0;                        // 134,217,728
    const size_t b16cat_off = 134217728;                // 1,048,576
    const size_t wcatF_off  = b16cat_off + 1048576;     // 1,048,576 (fp32)
    const size_t wembT_off  = wcatF_off + 1048576;      // 294,912
    const size_t wgen16_off = wembT_off + 294912;       // 49,152
    const size_t bcat_off   = wgen16_off + 49152;       // 4,096
    const size_t hg_off     = bcat_off + 4096;          // 2,097,152 (fp32)
    const size_t hidden_off = hg_off + 2097152;         // 524,288
    const size_t need_new   = hidden_off + 524288;      // ~139.3 MB

    if (ws_size >= need_new) {
        ushort_t* HWHp   = (ushort_t*)(ws + hwhp_off);
        ushort_t* B16cat = (ushort_t*)(ws + b16cat_off);
        float*    WcatF  = (float*)(ws + wcatF_off);
        float*    WembT  = (float*)(ws + wembT_off);
        ushort_t* Wgen16 = (ushort_t*)(ws + wgen16_off);
        float*    bcat   = (float*)(ws + bcat_off);
        float*    hg     = (float*)(ws + hg_off);
        float*    hidden = (float*)(ws + hidden_off);

        hipLaunchKernelGGL(prep_all, dim3(3972), dim3(256), 0, stream,
                           W_h2h, W_hh, W_ih, W_i2h, b_ih, b_h2h, b_hh, W_gen,
                           WcatF, B16cat, WembT, Wgen16, bcat, hidden);
        hipLaunchKernelGGL(hwhp_mfma, dim3((M / 128) * 8), dim3(256), 0, stream,
                           batch_H, B16cat, HWHp);
        for (int s = 0; s < STEPS; ++s) {
            // hg = hidden @ WcatF^T + bcat   [512,1024]
            hipLaunchKernelGGL(gemm_nt<float>, dim3(BATCH / BM, 1024 / BN), dim3(256), 0, stream,
                               hidden, HID, WcatF, HID, hg, 1024, bcat, BATCH, 1024, HID);
            hipLaunchKernelGGL(step_fused, dim3(BATCH), dim3(512), 0, stream,
                               HWHp, hg, WembT, Wgen16, W_score, b_gen, text, s, hidden, out);
        }
        return;
    }

    // ---------------- fallback: round-3 Plan B ----------------
    const size_t nHp = M * HID;
    const size_t small_floats = (size_t)BATCH * HID + BATCH * 1024 + BATCH * DIN
                              + BATCH * G3 + 1024 * HID + 1024;
    const size_t need_B32 = nHp * 4 + small_floats * 4;
    const bool use_fp32 = (ws_size >= need_B32);
    const size_t hp_bytes = use_fp32 ? nHp * 4 : nHp * 2;
    void* Hproj = (void*)ws;
    float* hiddenB = (float*)(ws + hp_bytes);
    float* hgB     = hiddenB + BATCH * HID;
    float* context = hgB + BATCH * 1024;
    float* gi      = context + BATCH * DIN;
    float* Wcat    = gi + BATCH * G3;
    float* bcatB   = Wcat + 1024 * HID;

    hipLaunchKernelGGL(prep_wcat, dim3(1024), dim3(256), 0, stream,
                       W_h2h, W_hh, b_h2h, b_hh, Wcat, bcatB, hiddenB);
    if (use_fp32) {
        hipLaunchKernelGGL(gemm_nt<float>, dim3(M / BM, HID / BN), dim3(256), 0, stream,
                           batch_H, DIN, W_i2h, DIN, (float*)Hproj, HID, (const float*)nullptr,
                           (int)M, HID, DIN);
    } else {
        hipLaunchKernelGGL(gemm_nt<ushort_t>, dim3(M / BM, HID / BN), dim3(256), 0, stream,
                           batch_H, DIN, W_i2h, DIN, (ushort_t*)Hproj, HID, (const float*)nullptr,
                           (int)M, HID, DIN);
    }
    for (int s = 0; s < STEPS; ++s) {
        hipLaunchKernelGGL(gemm_nt<float>, dim3(BATCH / BM, 1024 / BN), dim3(256), 0, stream,
                           hiddenB, HID, Wcat, HID, hgB, 1024, bcatB, BATCH, 1024, HID);
        if (use_fp32) {
            hipLaunchKernelGGL(attn_step<float>, dim3(BATCH), dim3(256), 0, stream,
                               (const float*)Hproj, batch_H, hgB, W_score, context);
        } else {
            hipLaunchKernelGGL(attn_step<ushort_t>, dim3(BATCH), dim3(256), 0, stream,
                               (const ushort_t*)Hproj, batch_H, hgB, W_score, context);
        }
        hipLaunchKernelGGL(gemm_nt<float>, dim3(BATCH / BM, G3 / BN), dim3(256), 0, stream,
                           context, DIN, W_ih, GRUIN, gi, G3, b_ih, BATCH, G3, DIN);
        hipLaunchKernelGGL(gru_gate_gen, dim3(BATCH), dim3(HID), 0, stream,
                           gi, hgB, hiddenB, out, text, s, W_ih, W_gen, b_gen);
    }
}